// Round 13
// baseline (12.242 us; speedup 1.0000x reference)
//
#include <hip/hip_runtime.h>

typedef unsigned int u32;
typedef unsigned long long u64;
typedef float f4 __attribute__((ext_vector_type(4)));   // native vec for nt-store

// AdderNet conv+ReLU: out[n,o,h,w] = relu(b[o] - sum_{c,kh,kw} |x - w|)
// x:[8,64,128,128] f32, w:[64,64,3,3], b:[64], out:[8,64,128,128] f32.
//
// Triangle-inequality screen over a SUBSET of terms (valid for all inputs):
//   sum_{all} |x_patch - w[o]| >= S'(n,h,w) - Wsum'[o]
// subset = channels 0..11, center input row (kh=1), in-bounds cols:
//   S'       = sum_{dc in {-1,0,1}, in-bounds} A12(n,h,w+dc)
//   A12      = sum_{c<12} |x[n,c,h,w]|
//   Wsum'[o] = sum_{c<12} sum_{kw} |w[o,c,1,kw]|
// If S' >= thr = max_o(Wsum'[o]+b[o]) + 1.0 (fp32 slack), all 64 outputs at
// that pixel are exactly 0. Failing pixels are recomputed exactly (fp32), so
// the kernel is correct for arbitrary inputs. Unit-scale margins: edge cols
// 4.3 sigma, interior 6.2 sigma -> fix-up effectively never taken.
//
// r13 lever: STORE RUN-LENGTH. r12's store instrs scattered 1KB across 8
// o-planes in 128B runs (page-thrash at 64KB stride). Now: 2-row blocks;
// wave wid stores o-planes {wid, wid+4, ...}; each instruction writes 1KB
// CONTIGUOUS in one o-plane (rows h0,h0+1 complete) - the fill pattern
// that measures 6.6 TB/s. nt-stores keep L2 clean for x/w.
// Barrier discipline: stores issue LAST; the post-store cross-wave fail
// check uses a RAW s_barrier with lgkmcnt(0) only (no vmcnt drain on the
// common path); the full __syncthreads drain is inside if(any) only.

#define Hh 128
#define Ww 128
#define C_IN 64
#define O_OUT 64
#define NB 8
#define PIX (Hh * Ww)

__global__ __launch_bounds__(256)
void adder_pair_screen(const float* __restrict__ x, const float* __restrict__ w,
                       const float* __restrict__ b, float* __restrict__ out) {
    __shared__ float Ap[4][256];     // [cg][row*128+col] partial A12 (ch cg,cg+4,cg+8)
    __shared__ float wmax[4];
    __shared__ u64   fmask[4];       // per-wave fail ballot

    const int tid  = threadIdx.x;
    const int bid  = blockIdx.x;
    const int n    = bid >> 6;       // image
    const int h0   = (bid & 63) * 2; // row pair
    const int wid  = tid >> 6;
    const int lane = tid & 63;

    // ---- 1) x loads first: 12 channels x 2 rows ----
    const int cg  = tid >> 6;        // 0..3 -> channels cg, cg+4, cg+8
    const int row = (tid >> 5) & 1;
    const int c4  = tid & 31;
    const float4* xn = (const float4*)x + (size_t)n * C_IN * (PIX / 4)
                     + (size_t)(h0 + row) * (Ww / 4) + c4;
    const float4 v0 = xn[(size_t)cg * (PIX / 4)];
    const float4 v1 = xn[(size_t)(cg + 4) * (PIX / 4)];
    const float4 v2 = xn[(size_t)(cg + 8) * (PIX / 4)];

    // ---- 2) threshold partials: thr = max_o( sum_{c<12}|w[o,c,1,:]| + b[o] ) ----
    {
        const int o = tid >> 2, jj = tid & 3;    // 64 o x 4 threads (3 ch each)
        float s = 0.f;
        #pragma unroll
        for (int k = 0; k < 3; ++k) {
            const float* wp = w + (size_t)o * 576 + (jj * 3 + k) * 9 + 3;  // kh=1
            s += fabsf(wp[0]) + fabsf(wp[1]) + fabsf(wp[2]);
        }
        s += __shfl_xor(s, 1); s += __shfl_xor(s, 2);
        float v = s + b[o];
        #pragma unroll
        for (int d = 4; d < 64; d <<= 1) v = fmaxf(v, __shfl_xor(v, d));
        if (lane == 0) wmax[wid] = v;
    }

    // ---- 3) A12 partials -> LDS ----
    {
        float4 a;
        a.x = fabsf(v0.x) + fabsf(v1.x) + fabsf(v2.x);
        a.y = fabsf(v0.y) + fabsf(v1.y) + fabsf(v2.y);
        a.z = fabsf(v0.z) + fabsf(v1.z) + fabsf(v2.z);
        a.w = fabsf(v0.w) + fabsf(v1.w) + fabsf(v2.w);
        *(float4*)&Ap[cg][row * 128 + c4 * 4] = a;
    }
    __syncthreads();   // B1: only x/w loads in flight (needed anyway)

    const float thr = fmaxf(fmaxf(wmax[0], wmax[1]),
                            fmaxf(wmax[2], wmax[3])) + 1.0f;

    // ---- 4) screen: thread tid -> pixel (row=tid>>7, col=tid&127) ----
    {
        const int prow = tid >> 7, col = tid & 127;
        const int base = prow * 128 + col;
        float S = 0.f;
        #pragma unroll
        for (int g = 0; g < 4; ++g) {
            const float* ap = &Ap[g][base];
            float sv = ap[0];
            if (col > 0)   sv += ap[-1];
            if (col < 127) sv += ap[1];
            S += sv;
        }
        const bool fail = !(S >= thr);           // cannot prove zero
        const u64 bal = __ballot(fail);
        if (lane == 0) fmask[wid] = bal;
    }

    // ---- 5) zero-store burst LAST: 1KB contiguous per instruction ----
    // wave wid owns o = {wid, wid+4, ..., wid+60}; per o: rows h0,h0+1
    // complete (64 f4 = 1KB, lane-contiguous). nt: don't evict x/w.
    f4* outn = (f4*)out + (size_t)n * O_OUT * (PIX / 4);
    const f4 z = (f4){0.f, 0.f, 0.f, 0.f};
    #pragma unroll
    for (int j = 0; j < 16; ++j) {
        const int o = j * 4 + wid;
        __builtin_nontemporal_store(z, &outn[(size_t)o * (PIX / 4) + h0 * 32 + lane]);
    }

    // ---- 6) cross-wave fail check WITHOUT draining stores ----
    asm volatile("s_waitcnt lgkmcnt(0)" ::: "memory");   // commit fmask (LDS only)
    __builtin_amdgcn_s_barrier();                        // raw: no vmcnt drain
    const u64 any = fmask[0] | fmask[1] | fmask[2] | fmask[3];

    // ---- 7) exact fp32 fix-up (block-uniform; normally never taken) ----
    if (any) {
        __syncthreads();   // full drain: zeros ordered before overwrites
        const float* xs = x + (size_t)n * C_IN * PIX;
        u64 m = fmask[wid];                      // wave's own screened pixels
        while (m) {
            const int bit = __ffsll((unsigned long long)m) - 1;
            m &= m - 1;
            const int p    = wid * 64 + bit;     // pixel index in tile
            const int prow = p >> 7, col = p & 127;
            const int h    = h0 + prow;
            const int o    = lane;               // 64 lanes = 64 outputs
            const float* wo = w + (size_t)o * C_IN * 9;
            float sum = 0.f;
            for (int c = 0; c < C_IN; ++c) {
                const float* xc = xs + (size_t)c * PIX;
                const float* wc = wo + c * 9;
                #pragma unroll
                for (int kh = 0; kh < 3; ++kh) {
                    const int gh = h + kh - 1;
                    #pragma unroll
                    for (int kw = 0; kw < 3; ++kw) {
                        const int gw = col + kw - 1;
                        const float xval = ((unsigned)gh < (unsigned)Hh &&
                                            (unsigned)gw < (unsigned)Ww)
                                           ? xc[gh * Ww + gw] : 0.f;
                        sum += fabsf(xval - wc[kh * 3 + kw]);
                    }
                }
            }
            out[(size_t)(n * O_OUT + o) * PIX + h * Ww + col] = fmaxf(b[o] - sum, 0.f);
        }
    }
}

extern "C" void kernel_launch(void* const* d_in, const int* in_sizes, int n_in,
                              void* d_out, int out_size, void* d_ws, size_t ws_size,
                              hipStream_t stream) {
    const float* x = (const float*)d_in[0];
    const float* w = (const float*)d_in[1];
    const float* b = (const float*)d_in[2];
    float* out = (float*)d_out;

    adder_pair_screen<<<NB * (Hh / 2), 256, 0, stream>>>(x, w, b, out);
}